// Round 9
// baseline (3913.048 us; speedup 1.0000x reference)
//
#include <hip/hip_runtime.h>

#define L_PAD 8192
#define HS    25
#define ES    50
#define G4    100   // 4*H
#define TILE  128
#define LOG2E 1.44269504088896340736f

typedef float v2f __attribute__((ext_vector_type(2)));

// -------- workspace layout --------
// zs2   : v2f[2][L_PAD*50]  packed gate preacts, NEW packing:
//         lane j<25 : (z_i[j], z_f[j])   lane j>=25 : (z_g[j-25], z_o[j-25])
// wstar : v2f[2][50]        h* @ Wh, same packing
// cstar : float[2][25]      frozen cell state

__device__ __forceinline__ float rl_f(float v, int lane) {
    return __int_as_float(__builtin_amdgcn_readlane(__float_as_int(v), lane));
}
__device__ __forceinline__ float fast_sigmoid(float x) {
    return __builtin_amdgcn_rcpf(1.f + __builtin_amdgcn_exp2f(x * (-LOG2E)));
}
__device__ __forceinline__ float fast_tanh(float x) {
    return fmaf(__builtin_amdgcn_rcpf(1.f + __builtin_amdgcn_exp2f(x * (-2.f * LOG2E))), 2.f, -1.f);
}

// ---------------- kernel 1: pre-activations (parallel) ----------------
__global__ __launch_bounds__(64) void k_pre(
    const int* __restrict__ tok, const int* __restrict__ plen,
    const float* __restrict__ Ef, const float* __restrict__ Wif, const float* __restrict__ bf,
    const float* __restrict__ Eb, const float* __restrict__ Wib, const float* __restrict__ bb,
    v2f* __restrict__ zs2)
{
    const int b = blockIdx.x;
    const int d = b & 1;
    const int t = b >> 1;
    const int j = threadIdx.x;
    const int len = *plen;

    int src;
    if (d == 0) src = t;
    else        src = (t < len) ? (len - 1 - t) : (L_PAD - 1 - (t - len));
    const int token = tok[src];

    const float* __restrict__ E  = d ? Eb  : Ef;
    const float* __restrict__ Wi = d ? Wib : Wif;
    const float* __restrict__ bs = d ? bb  : bf;

    __shared__ float e[ES];
    if (j < ES) e[j] = E[(size_t)token * ES + j];
    __syncthreads();
    if (j >= 50) return;

    const int c0 = (j < 25) ? j : j + 25;   // i-col or g-col
    const int c1 = c0 + 25;                 // f-col or o-col

    float ax = bs[c0], ay = bs[c1];
    float bx = 0.f,  by = 0.f;
    #pragma unroll
    for (int k = 0; k < ES; k += 2) {
        float e0 = e[k], e1 = e[k + 1];
        ax = fmaf(e0, Wi[k * G4 + c0],       ax);
        ay = fmaf(e0, Wi[k * G4 + c1],       ay);
        bx = fmaf(e1, Wi[(k + 1) * G4 + c0], bx);
        by = fmaf(e1, Wi[(k + 1) * G4 + c1], by);
    }
    zs2[(size_t)d * (L_PAD * 50) + t * 50 + j] = (v2f){ax + bx, ay + by};
}

// ---------------- kernel 2: the serial recurrence ----------------
// One wave per direction. Lane j<25: gates (i_j, f_j); lane j+25: (g_j, o_j).
// Rounds 1-8 evidence: the RA allocates 32-40 VGPRs no matter what hints are
// given, so ANY design needing >32 live regs (50 weights, 6-deep z-prefetch)
// silently spills to scratch and every serial step eats a ~800-cyc vmem
// round-trip (matches the constant ~800 cyc/step across all variants).
// This version is designed to FIT: z staged per 128-step tile into LDS
// (bulk, amortized), weights in LDS (conflict-free float2 rows, re-read per
// step via an opaque index so LICM can't hoist them into spilled regs).
// The serial chain touches only LDS (lgkm, pipelined) + VALU.
__global__ __launch_bounds__(64) void k_seq(
    const float* __restrict__ Whf, const float* __restrict__ Whb,
    const int* __restrict__ plen,
    const v2f* __restrict__ zs2_all,
    float* __restrict__ out,
    v2f* __restrict__ wstar, float* __restrict__ cstar)
{
    const int d = blockIdx.x;
    const int j = threadIdx.x;
    const int len = *plen;
    const float* __restrict__ Wh = d ? Whb : Whf;
    const v2f* __restrict__ z = zs2_all + (size_t)d * (L_PAD * 50);
    const int jj = (j < 50) ? j : 0;

    __shared__ v2f ZT[TILE * 50];   // 51.2 KB tile of z
    __shared__ v2f W2[HS][50];      // 10 KB weights: W2[k][q] = (Wh[k][c0(q)], Wh[k][c1(q)])

    for (int idx = j; idx < HS * 50; idx += 64) {
        int k = idx / 50, q = idx - k * 50;
        int qc0 = (q < 25) ? q : q + 25;
        W2[k][q] = (v2f){ Wh[k * G4 + qc0], Wh[k * G4 + qc0 + 25] };
    }

    // branch-free activation constants: first gate is sigmoid for lanes<25 (i),
    // tanh for lanes>=25 (g); second gate is sigmoid for all (f / o).
    const bool  lo  = (j < 25);
    const float my1 = lo ? (-LOG2E) : (-2.f * LOG2E);
    const float ca1 = lo ? 1.f : 2.f;
    const float cb1 = lo ? 0.f : -1.f;

    float c = 0.f, h = 0.f;          // lanes 0..24 carry real state
    const v2f* zp = ZT + jj;         // LDS: lane-strided base, 2-way bank alias = free
    float* outp = out + d * HS + j;  // out[t*50 + d*25 + j]

#define WDOT(k, A) { float hk = rl_f(h, k); v2f hk2 = {hk, hk}; \
    v2f w = *(const v2f*)((const char*)&W2[0][0] + (k) * 400 + oj8); \
    A += w * hk2; }

    for (int t0 = 0; t0 < len; t0 += TILE) {
        const int nt = (len - t0 < TILE) ? (len - t0) : TILE;

        // ---- phase A: bulk global -> LDS copy of this tile's z (coalesced) ----
        __syncthreads();
        {
            const v2f* __restrict__ zsrc = z + (size_t)t0 * 50;
            for (int i = j; i < nt * 50; i += 64) ZT[i] = zsrc[i];
        }
        __syncthreads();

        // ---- phase B: nt serial steps, LDS + VALU only ----
        float* op = outp + (size_t)t0 * 50;
        for (int s = 0; s < nt; ++s) {
            v2f zq = zp[s * 50];           // issued first; lands under the dot chain

            int oj8 = jj << 3;
            asm volatile("" : "+v"(oj8));  // opaque: blocks LICM of the 25 weight reads

            v2f A0 = {0.f, 0.f}, A1 = {0.f, 0.f}, A2 = {0.f, 0.f}, A3 = {0.f, 0.f};
            WDOT(0, A0)  WDOT(1, A1)  WDOT(2, A2)  WDOT(3, A3)
            WDOT(4, A0)  WDOT(5, A1)  WDOT(6, A2)  WDOT(7, A3)
            WDOT(8, A0)  WDOT(9, A1)  WDOT(10, A2) WDOT(11, A3)
            WDOT(12, A0) WDOT(13, A1) WDOT(14, A2) WDOT(15, A3)
            WDOT(16, A0) WDOT(17, A1) WDOT(18, A2) WDOT(19, A3)
            WDOT(20, A0) WDOT(21, A1) WDOT(22, A2) WDOT(23, A3)
            WDOT(24, A0)
            v2f pp = ((A0 + A1) + (A2 + A3)) + zq;

            // first gate: sigmoid(i) / tanh(g);  second gate: sigmoid(f) / sigmoid(o)
            float s1 = fmaf(__builtin_amdgcn_rcpf(1.f + __builtin_amdgcn_exp2f(pp.x * my1)), ca1, cb1);
            float s2 = fast_sigmoid(pp.y);

            float g_ = __shfl(s1, jj + 25);   // lane k pulls g_k from lane k+25
            float o_ = __shfl(s2, jj + 25);   // lane k pulls o_k from lane k+25
            float nc = fmaf(s2, c, s1 * g_);  // f*c + i*g
            float nh = o_ * fast_tanh(nc);
            c = nc;                            // unconditional; upper-lane garbage unread
            h = nh;
            if (j < 25) op[s * 50] = nh;
        }
    }

    // ---- epilogue: w* = h* @ Wh (lane's two columns) and c* ----
    v2f e = {0.f, 0.f};
    #pragma unroll
    for (int k = 0; k < HS; ++k) {
        float hk = rl_f(h, k);
        e += W2[k][jj] * (v2f){hk, hk};
    }
    if (j < 50) wstar[d * 50 + j] = e;
    if (j < 25) cstar[d * HS + j] = c;
#undef WDOT
}

// ---------------- kernel 3: frozen-carry tail (parallel) ----------------
__global__ __launch_bounds__(256) void k_tail(
    const int* __restrict__ plen,
    const v2f* __restrict__ zs2_all,
    const v2f* __restrict__ wstar, const float* __restrict__ cstar,
    float* __restrict__ out)
{
    const int tid = blockIdx.x * 256 + threadIdx.x;
    if (tid >= L_PAD * 50) return;
    const int col = tid % 50;
    const int t   = tid / 50;
    const int len = *plen;
    if (t < len) return;
    const int d = col / HS;
    const int k = col % HS;

    const v2f* __restrict__ z = zs2_all + (size_t)d * (L_PAD * 50);
    v2f a  = z[t * 50 + k];          // (zi, zf)
    v2f b  = z[t * 50 + k + 25];     // (zg, zo)
    v2f w1 = wstar[d * 50 + k];      // (wi, wf)
    v2f w2 = wstar[d * 50 + k + 25]; // (wg, wo)

    float i_ = fast_sigmoid(a.x + w1.x);
    float f_ = fast_sigmoid(a.y + w1.y);
    float g_ = fast_tanh  (b.x + w2.x);
    float o_ = fast_sigmoid(b.y + w2.y);

    float nc = fmaf(f_, cstar[d * HS + k], i_ * g_);
    out[t * 50 + col] = o_ * fast_tanh(nc);
}

extern "C" void kernel_launch(void* const* d_in, const int* in_sizes, int n_in,
                              void* d_out, int out_size, void* d_ws, size_t ws_size,
                              hipStream_t stream)
{
    const int*   tok  = (const int*)  d_in[0];
    const int*   plen = (const int*)  d_in[1];
    const float* Ef   = (const float*)d_in[2];
    const float* Wif  = (const float*)d_in[3];
    const float* Whf  = (const float*)d_in[4];
    const float* bf   = (const float*)d_in[5];
    const float* Eb   = (const float*)d_in[6];
    const float* Wib  = (const float*)d_in[7];
    const float* Whb  = (const float*)d_in[8];
    const float* bb   = (const float*)d_in[9];
    float* out = (float*)d_out;

    v2f*   zs2   = (v2f*)d_ws;
    v2f*   wstar = (v2f*)((char*)d_ws + (size_t)2 * L_PAD * 50 * sizeof(v2f));
    float* cstar = (float*)((char*)wstar + 100 * sizeof(v2f));

    k_pre <<<2 * L_PAD, 64, 0, stream>>>(tok, plen, Ef, Wif, bf, Eb, Wib, bb, zs2);
    k_seq <<<2, 64, 0, stream>>>(Whf, Whb, plen, zs2, out, wstar, cstar);
    k_tail<<<(L_PAD * 50 + 255) / 256, 256, 0, stream>>>(plen, zs2, wstar, cstar, out);
}

// Round 10
// 2646.463 us; speedup vs baseline: 1.4786x; 1.4786x over previous
//
#include <hip/hip_runtime.h>

#define L_PAD 8192
#define HS    25
#define ES    50
#define G4    100   // 4*H
#define TILE  128
#define LOG2E 1.44269504088896340736f

typedef float v2f __attribute__((ext_vector_type(2)));

// -------- workspace layout --------
// zs2   : v2f[2][L_PAD*50]  packed gate preacts:
//         lane j<25 : (z_i[j], z_f[j])   lane j>=25 : (z_g[j-25], z_o[j-25])
// wstar : v2f[2][50]        h* @ Wh, same packing
// cstar : float[2][25]      frozen cell state

__device__ __forceinline__ float rl_f(float v, int lane) {
    return __int_as_float(__builtin_amdgcn_readlane(__float_as_int(v), lane));
}
__device__ __forceinline__ float fast_sigmoid(float x) {
    return __builtin_amdgcn_rcpf(1.f + __builtin_amdgcn_exp2f(x * (-LOG2E)));
}
__device__ __forceinline__ float fast_tanh(float x) {
    return fmaf(__builtin_amdgcn_rcpf(1.f + __builtin_amdgcn_exp2f(x * (-2.f * LOG2E))), 2.f, -1.f);
}

// ---------------- kernel 1: pre-activations (parallel) ----------------
__global__ __launch_bounds__(64) void k_pre(
    const int* __restrict__ tok, const int* __restrict__ plen,
    const float* __restrict__ Ef, const float* __restrict__ Wif, const float* __restrict__ bf,
    const float* __restrict__ Eb, const float* __restrict__ Wib, const float* __restrict__ bb,
    v2f* __restrict__ zs2)
{
    const int b = blockIdx.x;
    const int d = b & 1;
    const int t = b >> 1;
    const int j = threadIdx.x;
    const int len = *plen;

    int src;
    if (d == 0) src = t;
    else        src = (t < len) ? (len - 1 - t) : (L_PAD - 1 - (t - len));
    const int token = tok[src];

    const float* __restrict__ E  = d ? Eb  : Ef;
    const float* __restrict__ Wi = d ? Wib : Wif;
    const float* __restrict__ bs = d ? bb  : bf;

    __shared__ float e[ES];
    if (j < ES) e[j] = E[(size_t)token * ES + j];
    __syncthreads();
    if (j >= 50) return;

    const int c0 = (j < 25) ? j : j + 25;   // i-col or g-col
    const int c1 = c0 + 25;                 // f-col or o-col

    float ax = bs[c0], ay = bs[c1];
    float bx = 0.f,  by = 0.f;
    #pragma unroll
    for (int k = 0; k < ES; k += 2) {
        float e0 = e[k], e1 = e[k + 1];
        ax = fmaf(e0, Wi[k * G4 + c0],       ax);
        ay = fmaf(e0, Wi[k * G4 + c1],       ay);
        bx = fmaf(e1, Wi[(k + 1) * G4 + c0], bx);
        by = fmaf(e1, Wi[(k + 1) * G4 + c1], by);
    }
    zs2[(size_t)d * (L_PAD * 50) + t * 50 + j] = (v2f){ax + bx, ay + by};
}

// ---------------- kernel 2: the serial recurrence ----------------
// One wave per direction. Lane j<25: gates (i_j, f_j); lane j+25: (g_j, o_j).
// Rounds 1-9 forensic summary:
//  - loop-invariant global weight loads get REMATERIALIZED in-loop (they're
//    single-inst remat candidates); pins after loads still allow scratch
//    spills; both put a vmcnt wait on the serial chain that ALSO drains the
//    z-prefetch (oldest-first) -> constant ~800 cyc/step (R3-R5, R8).
//  - per-step LDS weight reads serialize on lgkm waits -> 1100-1500 cyc (R6, R9).
//  - R9's VGPR_Count=132 proves there is NO allocator cap.
// Win condition: zero vmem loads in the loop, <=1 LDS read. Weights live in
// AGPRs: the "+a" asm pin's result is an opaque asm def -> NOT rematerializable,
// allocated from the separate AGPR pool (no VGPR pressure to evict them).
// z comes from a 128-step LDS tile (single ds_read_b64/step, issued early).
#define PINA(x) asm volatile("" : "+a"(x))
#define LWA(k)  float w0_##k = Wh[(k)*G4 + c0]; float w1_##k = Wh[(k)*G4 + c1]; \
                PINA(w0_##k); PINA(w1_##k);
#define FM(k, A) { float hk = rl_f(h, k); \
                   ax##A = fmaf(hk, w0_##k, ax##A); ay##A = fmaf(hk, w1_##k, ay##A); }
#define EPA(k)  { float hk = rl_f(h, k); \
                  ex = fmaf(hk, w0_##k, ex); ey = fmaf(hk, w1_##k, ey); }

__global__ __launch_bounds__(64) void k_seq(
    const float* __restrict__ Whf, const float* __restrict__ Whb,
    const int* __restrict__ plen,
    const v2f* __restrict__ zs2_all,
    float* __restrict__ out,
    v2f* __restrict__ wstar, float* __restrict__ cstar)
{
    const int d = blockIdx.x;
    const int j = threadIdx.x;
    const int len = *plen;
    const float* __restrict__ Wh = d ? Whb : Whf;
    const v2f* __restrict__ z = zs2_all + (size_t)d * (L_PAD * 50);
    const int jj = (j < 50) ? j : 0;
    const int c0 = (jj < 25) ? jj : jj + 25;   // this lane's first gate column
    const int c1 = c0 + 25;                    // second gate column

    __shared__ v2f ZT[TILE * 50];   // 51.2 KB z tile

    // 50 loop-invariant weights -> AGPRs (opaque defs, non-rematerializable)
    LWA(0)  LWA(1)  LWA(2)  LWA(3)  LWA(4)  LWA(5)  LWA(6)  LWA(7)  LWA(8)  LWA(9)
    LWA(10) LWA(11) LWA(12) LWA(13) LWA(14) LWA(15) LWA(16) LWA(17) LWA(18) LWA(19)
    LWA(20) LWA(21) LWA(22) LWA(23) LWA(24)

    // branch-free activation constants: first gate sigmoid(i)/tanh(g),
    // second gate sigmoid (f / o)
    const bool  lo  = (j < 25);
    const float my1 = lo ? (-LOG2E) : (-2.f * LOG2E);
    const float ca1 = lo ? 1.f : 2.f;
    const float cb1 = lo ? 0.f : -1.f;

    float c = 0.f, h = 0.f;          // lanes 0..24 carry real state
    const v2f* zp = ZT + jj;         // lane-strided LDS base (2-way alias = free)
    float* outp = out + d * HS + j;  // out[t*50 + d*25 + j]

    for (int t0 = 0; t0 < len; t0 += TILE) {
        const int nt = (len - t0 < TILE) ? (len - t0) : TILE;

        // ---- phase A: bulk global -> LDS copy of this tile's z (coalesced) ----
        __syncthreads();
        {
            const v2f* __restrict__ zsrc = z + (size_t)t0 * 50;
            for (int i = j; i < nt * 50; i += 64) ZT[i] = zsrc[i];
        }
        __syncthreads();

        // ---- phase B: nt serial steps; only LDS (1 read) + VALU + store ----
        float* op = outp + (size_t)t0 * 50;
        for (int s = 0; s < nt; ++s) {
            v2f zq = zp[s * 50];           // single ds_read_b64, lands under the chain

            float ax0 = 0.f, ay0 = 0.f, ax1 = 0.f, ay1 = 0.f;
            float ax2 = 0.f, ay2 = 0.f, ax3 = 0.f, ay3 = 0.f;
            FM(0,0)  FM(1,1)  FM(2,2)  FM(3,3)
            FM(4,0)  FM(5,1)  FM(6,2)  FM(7,3)
            FM(8,0)  FM(9,1)  FM(10,2) FM(11,3)
            FM(12,0) FM(13,1) FM(14,2) FM(15,3)
            FM(16,0) FM(17,1) FM(18,2) FM(19,3)
            FM(20,0) FM(21,1) FM(22,2) FM(23,3)
            FM(24,0)
            float px = ((ax0 + ax1) + (ax2 + ax3)) + zq.x;
            float py = ((ay0 + ay1) + (ay2 + ay3)) + zq.y;

            float s1 = fmaf(__builtin_amdgcn_rcpf(1.f + __builtin_amdgcn_exp2f(px * my1)), ca1, cb1);
            float s2 = fast_sigmoid(py);

            float g_ = __shfl(s1, jj + 25);   // lane k pulls g_k / (garbage for k>=25)
            float o_ = __shfl(s2, jj + 25);
            float nc = fmaf(s2, c, s1 * g_);  // f*c + i*g (lanes<25)
            float nh = o_ * fast_tanh(nc);
            c = nc;                            // unconditional; upper-lane garbage unread
            h = nh;
            if (j < 25) op[s * 50] = nh;
        }
    }

    // ---- epilogue: w* = h* @ Wh and c* for the frozen tail ----
    float ex = 0.f, ey = 0.f;
    EPA(0)  EPA(1)  EPA(2)  EPA(3)  EPA(4)  EPA(5)  EPA(6)  EPA(7)  EPA(8)  EPA(9)
    EPA(10) EPA(11) EPA(12) EPA(13) EPA(14) EPA(15) EPA(16) EPA(17) EPA(18) EPA(19)
    EPA(20) EPA(21) EPA(22) EPA(23) EPA(24)
    if (j < 50) wstar[d * 50 + j] = (v2f){ex, ey};
    if (j < 25) cstar[d * HS + j] = c;
}

// ---------------- kernel 3: frozen-carry tail (parallel) ----------------
__global__ __launch_bounds__(256) void k_tail(
    const int* __restrict__ plen,
    const v2f* __restrict__ zs2_all,
    const v2f* __restrict__ wstar, const float* __restrict__ cstar,
    float* __restrict__ out)
{
    const int tid = blockIdx.x * 256 + threadIdx.x;
    if (tid >= L_PAD * 50) return;
    const int col = tid % 50;
    const int t   = tid / 50;
    const int len = *plen;
    if (t < len) return;
    const int d = col / HS;
    const int k = col % HS;

    const v2f* __restrict__ z = zs2_all + (size_t)d * (L_PAD * 50);
    v2f a  = z[t * 50 + k];          // (zi, zf)
    v2f b  = z[t * 50 + k + 25];     // (zg, zo)
    v2f w1 = wstar[d * 50 + k];      // (wi, wf)
    v2f w2 = wstar[d * 50 + k + 25]; // (wg, wo)

    float i_ = fast_sigmoid(a.x + w1.x);
    float f_ = fast_sigmoid(a.y + w1.y);
    float g_ = fast_tanh  (b.x + w2.x);
    float o_ = fast_sigmoid(b.y + w2.y);

    float nc = fmaf(f_, cstar[d * HS + k], i_ * g_);
    out[t * 50 + col] = o_ * fast_tanh(nc);
}

extern "C" void kernel_launch(void* const* d_in, const int* in_sizes, int n_in,
                              void* d_out, int out_size, void* d_ws, size_t ws_size,
                              hipStream_t stream)
{
    const int*   tok  = (const int*)  d_in[0];
    const int*   plen = (const int*)  d_in[1];
    const float* Ef   = (const float*)d_in[2];
    const float* Wif  = (const float*)d_in[3];
    const float* Whf  = (const float*)d_in[4];
    const float* bf   = (const float*)d_in[5];
    const float* Eb   = (const float*)d_in[6];
    const float* Wib  = (const float*)d_in[7];
    const float* Whb  = (const float*)d_in[8];
    const float* bb   = (const float*)d_in[9];
    float* out = (float*)d_out;

    v2f*   zs2   = (v2f*)d_ws;
    v2f*   wstar = (v2f*)((char*)d_ws + (size_t)2 * L_PAD * 50 * sizeof(v2f));
    float* cstar = (float*)((char*)wstar + 100 * sizeof(v2f));

    k_pre <<<2 * L_PAD, 64, 0, stream>>>(tok, plen, Ef, Wif, bf, Eb, Wib, bb, zs2);
    k_seq <<<2, 64, 0, stream>>>(Whf, Whb, plen, zs2, out, wstar, cstar);
    k_tail<<<(L_PAD * 50 + 255) / 256, 256, 0, stream>>>(plen, zs2, wstar, cstar, out);
}